// Round 4
// baseline (1396.545 us; speedup 1.0000x reference)
//
#include <hip/hip_runtime.h>
#include <hip/hip_bf16.h>
#include <stdint.h>

typedef __hip_bfloat16 bf16;
typedef unsigned short ushort_t;

#define B_ 32
#define F_ 4096
#define S_ 8
#define D_ 512
#define H_ 2048
#define LN_EPS 1e-5f
#define EPS_ 1e-8f
#define SCALE_ 0.044194173824159216f  // 512^-0.5

__device__ __forceinline__ float b2f(ushort_t u){
  union { uint32_t i; float f; } c; c.i = ((uint32_t)u) << 16; return c.f;
}
__device__ __forceinline__ float4 ld4f(const float* p){ return *(const float4*)p; }
__device__ __forceinline__ float4 ld4h(const ushort_t* p){
  ushort4 u = *(const ushort4*)p;
  return make_float4(b2f(u.x), b2f(u.y), b2f(u.z), b2f(u.w));
}
__device__ __forceinline__ float allsum64(float v){
  #pragma unroll
  for (int o = 1; o < 64; o <<= 1) v += __shfl_xor(v, o, 64);
  return v;
}
__device__ __forceinline__ float blockSum256(float v, float* sh){
  v = allsum64(v);
  int wid = threadIdx.x >> 6, lane = threadIdx.x & 63;
  __syncthreads();
  if (lane == 0) sh[wid] = v;
  __syncthreads();
  return sh[0] + sh[1] + sh[2] + sh[3];
}
__device__ __forceinline__ float dynld(const void* p, int i, bool f32){
  return f32 ? ((const float*)p)[i] : b2f(((const ushort_t*)p)[i]);
}

// flag=1 -> tensors are fp32; flag=0 -> bf16 (heuristic on bit patterns).
__global__ void detect_dtype(const uint32_t* __restrict__ w, int* __restrict__ flag){
  __shared__ int sh;
  if (threadIdx.x == 0) sh = 0;
  __syncthreads();
  int c = 0;
  for (int i = threadIdx.x; i < 4096; i += 256){
    uint32_t e = (w[i] >> 7) & 0xFF;
    if (e == 0 || e >= 0xBF) c++;
  }
  atomicAdd(&sh, c);
  __syncthreads();
  if (threadIdx.x == 0) *flag = (sh >= 100) ? 1 : 0;
}

// C = A @ B(^T).  A_CMB: A element = relu(sum of 4 split-K partials + Abias[k]).
template<int TRANS_B, int A_DYN, int B_DYN, int A_CMB>
__global__ __launch_bounds__(256) void gemm64(
    const void* __restrict__ A, const void* __restrict__ B,
    const void* __restrict__ Abias, float* __restrict__ C,
    int M, int N, int K, int kLen, size_t aPart, const int* __restrict__ flag)
{
  const bool f32 = (*flag != 0);
  const bool aF = A_DYN ? f32 : true;
  const bool bF = B_DYN ? f32 : true;
  __shared__ float As[16][68];
  __shared__ float Bs[16][68];
  const int tid = threadIdx.x;
  const int m0 = blockIdx.x * 64, n0 = blockIdx.y * 64;
  const int kBeg = blockIdx.z * kLen;
  const int tm = (tid & 15) * 4, tn = (tid >> 4) * 4;
  const int ar = tid >> 2;
  const int ac = (tid & 3) * 4;
  const int br = tid >> 4;
  const int bc = (tid & 15) * 4;
  float acc[4][4] = {};

  for (int kc = kBeg; kc < kBeg + kLen; kc += 16){
    size_t aidx = (size_t)(m0 + ar) * K + kc + ac;
    float4 a4;
    if (A_CMB){
      const float* Af = (const float*)A;
      float4 s0 = ld4f(Af + aidx);
      float4 s1 = ld4f(Af + aPart + aidx);
      float4 s2 = ld4f(Af + 2 * aPart + aidx);
      float4 s3 = ld4f(Af + 3 * aPart + aidx);
      float bx0 = dynld(Abias, kc + ac + 0, f32);
      float bx1 = dynld(Abias, kc + ac + 1, f32);
      float bx2 = dynld(Abias, kc + ac + 2, f32);
      float bx3 = dynld(Abias, kc + ac + 3, f32);
      a4.x = fmaxf(s0.x + s1.x + s2.x + s3.x + bx0, 0.0f);
      a4.y = fmaxf(s0.y + s1.y + s2.y + s3.y + bx1, 0.0f);
      a4.z = fmaxf(s0.z + s1.z + s2.z + s3.z + bx2, 0.0f);
      a4.w = fmaxf(s0.w + s1.w + s2.w + s3.w + bx3, 0.0f);
    } else {
      a4 = aF ? ld4f((const float*)A + aidx) : ld4h((const ushort_t*)A + aidx);
    }
    As[ac+0][ar] = a4.x; As[ac+1][ar] = a4.y; As[ac+2][ar] = a4.z; As[ac+3][ar] = a4.w;
    if (!TRANS_B){
      size_t bidx = (size_t)(kc + br) * N + n0 + bc;
      float4 b4 = bF ? ld4f((const float*)B + bidx) : ld4h((const ushort_t*)B + bidx);
      Bs[br][bc+0] = b4.x; Bs[br][bc+1] = b4.y; Bs[br][bc+2] = b4.z; Bs[br][bc+3] = b4.w;
    } else {
      size_t bidx = (size_t)(n0 + ar) * K + kc + ac;
      float4 b4 = bF ? ld4f((const float*)B + bidx) : ld4h((const ushort_t*)B + bidx);
      Bs[ac+0][ar] = b4.x; Bs[ac+1][ar] = b4.y; Bs[ac+2][ar] = b4.z; Bs[ac+3][ar] = b4.w;
    }
    __syncthreads();
    #pragma unroll
    for (int k = 0; k < 16; k++){
      float av[4], bv[4];
      #pragma unroll
      for (int i = 0; i < 4; i++) av[i] = As[k][tm + i];
      #pragma unroll
      for (int j = 0; j < 4; j++) bv[j] = Bs[k][tn + j];
      #pragma unroll
      for (int i = 0; i < 4; i++)
        #pragma unroll
        for (int j = 0; j < 4; j++) acc[i][j] += av[i] * bv[j];
    }
    __syncthreads();
  }
  #pragma unroll
  for (int i = 0; i < 4; i++)
    #pragma unroll
    for (int j = 0; j < 4; j++)
      C[((size_t)blockIdx.z * M + m0 + tm + i) * N + n0 + tn + j] = acc[i][j];
}

// sum 4 split-K partials (used once, for Wqk preamble)
__global__ __launch_bounds__(256) void combine4(
    const float* __restrict__ in, float* __restrict__ out, int sz)
{
  int i = blockIdx.x * 256 + threadIdx.x;
  out[i] = in[i] + in[sz + i] + in[2 * sz + i] + in[3 * sz + i];
}

// fused gi/gh GEMM: z in [0,8): z&3 = k-split, z>=4 selects gh (A=s_n, B=w_hh^T)
// else gi (A=Ud, B=Wvih dense fp32). N=1536, K=512, M=256.
__global__ __launch_bounds__(256) void gemm_gigh(
    const float* __restrict__ Ud, const float* __restrict__ Wvih,
    const float* __restrict__ s_n, const void* __restrict__ w_hh,
    float* __restrict__ gip, float* __restrict__ ghp,
    const int* __restrict__ flag)
{
  const bool f32 = (*flag != 0);
  const bool doGh = blockIdx.z >= 4;
  const int kz = blockIdx.z & 3;
  __shared__ float As[16][68];
  __shared__ float Bs[16][68];
  const int tid = threadIdx.x;
  const int m0 = blockIdx.x * 64, n0 = blockIdx.y * 64;
  const int kBeg = kz * 128;
  const int tm = (tid & 15) * 4, tn = (tid >> 4) * 4;
  const int ar = tid >> 2;
  const int ac = (tid & 3) * 4;
  const int br = tid >> 4;
  const int bc = (tid & 15) * 4;
  const float* A = doGh ? s_n : Ud;
  float acc[4][4] = {};

  for (int kc = kBeg; kc < kBeg + 128; kc += 16){
    float4 a4 = ld4f(A + (size_t)(m0 + ar) * 512 + kc + ac);
    As[ac+0][ar] = a4.x; As[ac+1][ar] = a4.y; As[ac+2][ar] = a4.z; As[ac+3][ar] = a4.w;
    if (!doGh){
      float4 b4 = ld4f(Wvih + (size_t)(kc + br) * 1536 + n0 + bc);
      Bs[br][bc+0] = b4.x; Bs[br][bc+1] = b4.y; Bs[br][bc+2] = b4.z; Bs[br][bc+3] = b4.w;
    } else {
      size_t bidx = (size_t)(n0 + ar) * 512 + kc + ac;
      float4 b4 = f32 ? ld4f((const float*)w_hh + bidx)
                      : ld4h((const ushort_t*)w_hh + bidx);
      Bs[ac+0][ar] = b4.x; Bs[ac+1][ar] = b4.y; Bs[ac+2][ar] = b4.z; Bs[ac+3][ar] = b4.w;
    }
    __syncthreads();
    #pragma unroll
    for (int k = 0; k < 16; k++){
      float av[4], bv[4];
      #pragma unroll
      for (int i = 0; i < 4; i++) av[i] = As[k][tm + i];
      #pragma unroll
      for (int j = 0; j < 4; j++) bv[j] = Bs[k][tn + j];
      #pragma unroll
      for (int i = 0; i < 4; i++)
        #pragma unroll
        for (int j = 0; j < 4; j++) acc[i][j] += av[i] * bv[j];
    }
    __syncthreads();
  }
  float* C = (doGh ? ghp : gip) + (size_t)kz * 256 * 1536;
  #pragma unroll
  for (int i = 0; i < 4; i++)
    #pragma unroll
    for (int j = 0; j < 4; j++)
      C[(size_t)(m0 + tm + i) * 1536 + n0 + tn + j] = acc[i][j];
}

// ---- NEW: per-feature-row LayerNorm stats (iteration-invariant, runs once) ----
__global__ __launch_bounds__(256, 2) void ln_stats(
    const void* __restrict__ features, float* __restrict__ meanb,
    float* __restrict__ rstdb, const int* __restrict__ flag)
{
  const bool f32 = (*flag != 0);
  const int b = blockIdx.y;
  const int tid = threadIdx.x, wid = tid >> 6, lane = tid & 63;
  const int f0 = blockIdx.x * 128 + wid * 32;
  const size_t base = ((size_t)b * F_ + f0) * D_ + 8 * lane;
  if (f32){
    const float* fp = (const float*)features + base;
    for (int r = 0; r < 32; r++){
      float4 c0 = ld4f(fp + (size_t)r * D_);
      float4 c1 = ld4f(fp + (size_t)r * D_ + 4);
      float s1 = c0.x+c0.y+c0.z+c0.w + c1.x+c1.y+c1.z+c1.w;
      float s2 = c0.x*c0.x+c0.y*c0.y+c0.z*c0.z+c0.w*c0.w
               + c1.x*c1.x+c1.y*c1.y+c1.z*c1.z+c1.w*c1.w;
      s1 = allsum64(s1); s2 = allsum64(s2);
      if (lane == 0){
        float mean = s1 * (1.0f/512.0f);
        float var = fmaxf(s2 * (1.0f/512.0f) - mean*mean, 0.0f);
        meanb[b * F_ + f0 + r] = mean;
        rstdb[b * F_ + f0 + r] = 1.0f / sqrtf(var + LN_EPS);
      }
    }
  } else {
    const ushort_t* fp = (const ushort_t*)features + base;
    for (int r = 0; r < 32; r++){
      uint4 u = *(const uint4*)(fp + (size_t)r * D_);
      float x0=b2f(u.x&0xffff), x1=b2f(u.x>>16), x2=b2f(u.y&0xffff), x3=b2f(u.y>>16);
      float x4=b2f(u.z&0xffff), x5=b2f(u.z>>16), x6=b2f(u.w&0xffff), x7=b2f(u.w>>16);
      float s1 = x0+x1+x2+x3+x4+x5+x6+x7;
      float s2 = x0*x0+x1*x1+x2*x2+x3*x3+x4*x4+x5*x5+x6*x6+x7*x7;
      s1 = allsum64(s1); s2 = allsum64(s2);
      if (lane == 0){
        float mean = s1 * (1.0f/512.0f);
        float var = fmaxf(s2 * (1.0f/512.0f) - mean*mean, 0.0f);
        meanb[b * F_ + f0 + r] = mean;
        rstdb[b * F_ + f0 + r] = 1.0f / sqrtf(var + LN_EPS);
      }
    }
  }
}

// ---- NEW: per-iter prep: g = SCALE*qk*lw_feat; gs = sum(g); qb = SCALE*qk.lb ----
__global__ __launch_bounds__(256) void qk_prep(
    const float* __restrict__ qkp, const void* __restrict__ lnw,
    const void* __restrict__ lnb, float* __restrict__ gbuf,
    float* __restrict__ gsb, float* __restrict__ qbb,
    const int* __restrict__ flag)
{
  const bool f32 = (*flag != 0);
  __shared__ float sh[4];
  const int b = blockIdx.x, t = threadIdx.x;
  #pragma unroll
  for (int s = 0; s < 8; s++){
    float gsum = 0.0f, qbsum = 0.0f;
    #pragma unroll
    for (int u = 0; u < 2; u++){
      int d = t + u * 256;
      size_t idx = (size_t)(b * 8 + s) * 512 + d;
      float q = qkp[idx] + qkp[131072 + idx] + qkp[262144 + idx] + qkp[393216 + idx];
      float lwv = dynld(lnw, d, f32), lbv = dynld(lnb, d, f32);
      float g = SCALE_ * q * lwv;
      gbuf[(size_t)b * 4096 + s * 512 + d] = g;
      gsum += g;
      qbsum += SCALE_ * q * lbv;
    }
    float gs = blockSum256(gsum, sh);
    float qb = blockSum256(qbsum, sh);
    if (t == 0){ gsb[b * 8 + s] = gs; qbb[b * 8 + s] = qb; }
  }
}

// ---- NEW big_pass2: thread-per-row, zero shuffles in hot loops ----
template<int F32>
__device__ __forceinline__ void bp2_phase1(
    const void* __restrict__ features, const float* __restrict__ gb,
    size_t rowbase, float (&acc)[8])
{
  if (F32){
    const float* fp = (const float*)features + rowbase;
    for (int c = 0; c < 128; c++){
      float4 xv = ld4f(fp + c * 4);
      #pragma unroll
      for (int s = 0; s < 8; s++){
        float4 g4 = ld4f(gb + s * 512 + c * 4);
        acc[s] += g4.x*xv.x + g4.y*xv.y + g4.z*xv.z + g4.w*xv.w;
      }
    }
  } else {
    const ushort_t* fp = (const ushort_t*)features + rowbase;
    for (int c = 0; c < 64; c++){
      uint4 u = *(const uint4*)(fp + c * 8);
      float x0=b2f(u.x&0xffff), x1=b2f(u.x>>16), x2=b2f(u.y&0xffff), x3=b2f(u.y>>16);
      float x4=b2f(u.z&0xffff), x5=b2f(u.z>>16), x6=b2f(u.w&0xffff), x7=b2f(u.w>>16);
      #pragma unroll
      for (int s = 0; s < 8; s++){
        float4 ga = ld4f(gb + s * 512 + c * 8);
        float4 gc = ld4f(gb + s * 512 + c * 8 + 4);
        acc[s] += ga.x*x0 + ga.y*x1 + ga.z*x2 + ga.w*x3
                + gc.x*x4 + gc.y*x5 + gc.z*x6 + gc.w*x7;
      }
    }
  }
}

template<int F32>
__device__ __forceinline__ void bp2_phase2(
    const void* __restrict__ features, size_t tb, const float* __restrict__ Pl,
    int s2, int dq, float (&a1)[16])
{
  if (F32){
    const float* fp = (const float*)features + tb + dq * 16;
    for (int r = 0; r < 256; r++){
      float pw = Pl[s2 * 256 + r];
      const float* rp = fp + (size_t)r * D_;
      float4 x0 = ld4f(rp), x1 = ld4f(rp + 4), x2 = ld4f(rp + 8), x3 = ld4f(rp + 12);
      a1[0]  += pw*x0.x; a1[1]  += pw*x0.y; a1[2]  += pw*x0.z; a1[3]  += pw*x0.w;
      a1[4]  += pw*x1.x; a1[5]  += pw*x1.y; a1[6]  += pw*x1.z; a1[7]  += pw*x1.w;
      a1[8]  += pw*x2.x; a1[9]  += pw*x2.y; a1[10] += pw*x2.z; a1[11] += pw*x2.w;
      a1[12] += pw*x3.x; a1[13] += pw*x3.y; a1[14] += pw*x3.z; a1[15] += pw*x3.w;
    }
  } else {
    const ushort_t* fp = (const ushort_t*)features + tb + dq * 16;
    for (int r = 0; r < 256; r++){
      float pw = Pl[s2 * 256 + r];
      const ushort_t* rp = fp + (size_t)r * D_;
      uint4 u0 = *(const uint4*)rp;
      uint4 u1 = *(const uint4*)(rp + 8);
      a1[0]  += pw*b2f(u0.x&0xffff); a1[1]  += pw*b2f(u0.x>>16);
      a1[2]  += pw*b2f(u0.y&0xffff); a1[3]  += pw*b2f(u0.y>>16);
      a1[4]  += pw*b2f(u0.z&0xffff); a1[5]  += pw*b2f(u0.z>>16);
      a1[6]  += pw*b2f(u0.w&0xffff); a1[7]  += pw*b2f(u0.w>>16);
      a1[8]  += pw*b2f(u1.x&0xffff); a1[9]  += pw*b2f(u1.x>>16);
      a1[10] += pw*b2f(u1.y&0xffff); a1[11] += pw*b2f(u1.y>>16);
      a1[12] += pw*b2f(u1.z&0xffff); a1[13] += pw*b2f(u1.z>>16);
      a1[14] += pw*b2f(u1.w&0xffff); a1[15] += pw*b2f(u1.w>>16);
    }
  }
}

// grid (16 fgroups, 32 b), 256 threads; block owns 256 feature rows.
// Phase 1: thread-per-row dots (no cross-lane). Softmax scalar per thread.
// Phase 2: block GEMM A1[8][512] = P[8][256] @ X[256][512].
__global__ __launch_bounds__(256, 2) void big_pass2(
    const void* __restrict__ features, const float* __restrict__ gbuf,
    const float* __restrict__ gsb, const float* __restrict__ qbb,
    const float* __restrict__ meanb, const float* __restrict__ rstdb,
    void* __restrict__ d_out_base, float* __restrict__ A1p,
    float* __restrict__ A2p, float* __restrict__ A3p,
    const int* __restrict__ flag)
{
  const bool f32 = (*flag != 0);
  __shared__ float Pl[8 * 256];
  __shared__ float sh[4];
  const int b = blockIdx.y, fg = blockIdx.x, t = threadIdx.x;
  const int f0 = fg * 256;
  const int row = f0 + t;
  const float* gb = gbuf + (size_t)b * 4096;
  const float mean = meanb[b * F_ + row];
  const float rstd = rstdb[b * F_ + row];

  float acc[8] = {};
  const size_t rowbase = ((size_t)b * F_ + row) * D_;
  if (f32) bp2_phase1<1>(features, gb, rowbase, acc);
  else     bp2_phase1<0>(features, gb, rowbase, acc);

  float dt[8];
  #pragma unroll
  for (int s = 0; s < 8; s++)
    dt[s] = rstd * (acc[s] - mean * gsb[b * 8 + s]) + qbb[b * 8 + s];
  float mx = dt[0];
  #pragma unroll
  for (int s = 1; s < 8; s++) mx = fmaxf(mx, dt[s]);
  float p[8]; float den = 0.0f;
  #pragma unroll
  for (int s = 0; s < 8; s++){ p[s] = __expf(dt[s] - mx); den += p[s]; }
  float inv = 1.0f / den;
  #pragma unroll
  for (int s = 0; s < 8; s++) p[s] *= inv;
  // attention-prob output (pre_norm_attn)
  #pragma unroll
  for (int s = 0; s < 8; s++){
    size_t oi = 131072 + ((size_t)(b * 8 + s)) * F_ + row;
    if (f32) ((float*)d_out_base)[oi] = p[s];
    else     ((bf16*)d_out_base)[oi] = __float2bfloat16(p[s]);
  }
  float a2[8], a3[8];
  #pragma unroll
  for (int s = 0; s < 8; s++){
    float pe = p[s] + EPS_;
    Pl[s * 256 + t] = pe * rstd;
    a2[s] = pe * rstd * mean;
    a3[s] = pe;
  }
  const int bidx = b * 16 + fg;
  #pragma unroll
  for (int s = 0; s < 8; s++){
    float v2 = blockSum256(a2[s], sh);
    float v3 = blockSum256(a3[s], sh);
    if (t == s){ A2p[bidx * 8 + s] = v2; A3p[bidx * 8 + s] = v3; }
  }
  __syncthreads();
  // phase 2: thread owns (s2 = t>>5, d = (t&31)*16 .. +15)
  const int s2 = t >> 5, dq = t & 31;
  float a1[16] = {};
  const size_t tb = ((size_t)b * F_ + f0) * D_;
  if (f32) bp2_phase2<1>(features, tb, Pl, s2, dq, a1);
  else     bp2_phase2<0>(features, tb, Pl, s2, dq, a1);
  float* up = A1p + ((size_t)bidx) * 4096 + s2 * 512 + dq * 16;
  #pragma unroll
  for (int j = 0; j < 4; j++)
    *(float4*)(up + j * 4) = make_float4(a1[4*j], a1[4*j+1], a1[4*j+2], a1[4*j+3]);
}

// Ud[b,s,d] = lw_feat[d]*(sum A1 - sum A2)/R + lb_feat[d], R = sum A3
__global__ __launch_bounds__(256) void reduce_updates2(
    const float* __restrict__ A1p, const float* __restrict__ A2p,
    const float* __restrict__ A3p, const void* __restrict__ lnw,
    const void* __restrict__ lnb, float* __restrict__ Ud,
    const int* __restrict__ flag)
{
  const bool f32 = (*flag != 0);
  __shared__ float sc[2];
  const int blk = blockIdx.x;
  const int b = blk >> 3, s = blk & 7;
  const int t = threadIdx.x;
  if (t == 0){
    float R = 0.0f, C = 0.0f;
    for (int fg = 0; fg < 16; fg++){
      R += A3p[(b * 16 + fg) * 8 + s];
      C += A2p[(b * 16 + fg) * 8 + s];
    }
    sc[0] = 1.0f / R; sc[1] = C;
  }
  __syncthreads();
  const float rinv = sc[0], C = sc[1];
  #pragma unroll
  for (int u = 0; u < 2; u++){
    int d = t + u * 256;
    float a = 0.0f;
    for (int fg = 0; fg < 16; fg++)
      a += A1p[((size_t)(b * 16 + fg)) * 4096 + s * 512 + d];
    float lwv = dynld(lnw, d, f32), lbv = dynld(lnb, d, f32);
    Ud[((size_t)(b * 8 + s)) * 512 + d] = lwv * (a - C) * rinv + lbv;
  }
}

__global__ __launch_bounds__(256) void ln_rows(
    const float* __restrict__ x, const void* __restrict__ w,
    const void* __restrict__ b, float* __restrict__ y, const int* __restrict__ flag)
{
  const bool f32 = (*flag != 0);
  __shared__ float sh[4];
  int row = blockIdx.x, t = threadIdx.x;
  const float* xr = x + (size_t)row * D_;
  float v0 = xr[t], v1 = xr[t + 256];
  float mean = blockSum256(v0 + v1, sh) * (1.0f / 512.0f);
  float d0 = v0 - mean, d1 = v1 - mean;
  float var = blockSum256(d0 * d0 + d1 * d1, sh) * (1.0f / 512.0f);
  float rstd = 1.0f / sqrtf(var + LN_EPS);
  float w0 = dynld(w, t, f32),       w1 = dynld(w, t + 256, f32);
  float b0 = dynld(b, t, f32),       b1 = dynld(b, t + 256, f32);
  y[(size_t)row * D_ + t]       = d0 * rstd * w0 + b0;
  y[(size_t)row * D_ + t + 256] = d1 * rstd * w1 + b1;
}

// fused: sum gi/gh split-K partials + biases -> GRU gates -> snew, then LN(snew)
__global__ __launch_bounds__(256) void gru_combine(
    const float* __restrict__ gip, const float* __restrict__ ghp,
    const void* __restrict__ b_ih, const void* __restrict__ b_hh,
    const float* __restrict__ sn, const void* __restrict__ lw,
    const void* __restrict__ lb, float* __restrict__ snew,
    float* __restrict__ lnm, const int* __restrict__ flag)
{
  const bool f32 = (*flag != 0);
  __shared__ float sh[4];
  int row = blockIdx.x, t = threadIdx.x;
  const float* snr = sn + (size_t)row * D_;
  float v[2];
  #pragma unroll
  for (int u = 0; u < 2; u++){
    int d = t + u * 256;
    float ir = 0, iz = 0, in_ = 0, hr = 0, hz = 0, hn = 0;
    #pragma unroll
    for (int p = 0; p < 4; p++){
      const float* gp = gip + (size_t)p * 393216 + (size_t)row * 1536;
      const float* hp = ghp + (size_t)p * 393216 + (size_t)row * 1536;
      ir  += gp[d]; iz += gp[512 + d]; in_ += gp[1024 + d];
      hr  += hp[d]; hz += hp[512 + d]; hn  += hp[1024 + d];
    }
    ir  += dynld(b_ih, d, f32);
    iz  += dynld(b_ih, 512 + d, f32);
    in_ += dynld(b_ih, 1024 + d, f32);
    hr  += dynld(b_hh, d, f32);
    hz  += dynld(b_hh, 512 + d, f32);
    hn  += dynld(b_hh, 1024 + d, f32);
    float rg = 1.0f / (1.0f + __expf(-(ir + hr)));
    float zg = 1.0f / (1.0f + __expf(-(iz + hz)));
    float a  = in_ + rg * hn;
    float e2 = __expf(2.0f * a);
    float ng = 1.0f - 2.0f / (e2 + 1.0f);
    float h  = snr[d];
    v[u] = (1.0f - zg) * ng + zg * h;
    snew[(size_t)row * D_ + d] = v[u];
  }
  float mean = blockSum256(v[0] + v[1], sh) * (1.0f / 512.0f);
  float d0 = v[0] - mean, d1 = v[1] - mean;
  float var = blockSum256(d0 * d0 + d1 * d1, sh) * (1.0f / 512.0f);
  float rstd = 1.0f / sqrtf(var + LN_EPS);
  float w0 = dynld(lw, t, f32),       w1 = dynld(lw, t + 256, f32);
  float b0 = dynld(lb, t, f32),       b1 = dynld(lb, t + 256, f32);
  lnm[(size_t)row * D_ + t]       = d0 * rstd * w0 + b0;
  lnm[(size_t)row * D_ + t + 256] = d1 * rstd * w1 + b1;
}

// fused: slots_new = snew + sum(8 h2 partials) + b2; then either LN -> s_n
// (next iteration) or dtype-cast store to d_out (final iteration).
template<int FINAL>
__global__ __launch_bounds__(256) void combine_ln(
    const float* __restrict__ snew, const float* __restrict__ h2p,
    const void* __restrict__ b2, const void* __restrict__ lnw,
    const void* __restrict__ lnb, float* __restrict__ s_n,
    void* __restrict__ out, const int* __restrict__ flag)
{
  const bool f32 = (*flag != 0);
  __shared__ float sh[4];
  int row = blockIdx.x, t = threadIdx.x;
  float v[2];
  #pragma unroll
  for (int u = 0; u < 2; u++){
    int d = t + u * 256;
    size_t idx = (size_t)row * D_ + d;
    float acc = snew[idx];
    #pragma unroll
    for (int p = 0; p < 8; p++) acc += h2p[(size_t)p * 131072 + idx];
    acc += dynld(b2, d, f32);
    v[u] = acc;
    if (FINAL){
      if (f32) ((float*)out)[idx] = acc;
      else     ((bf16*)out)[idx] = __float2bfloat16(acc);
    }
  }
  if (!FINAL){
    float mean = blockSum256(v[0] + v[1], sh) * (1.0f / 512.0f);
    float d0 = v[0] - mean, d1 = v[1] - mean;
    float var = blockSum256(d0 * d0 + d1 * d1, sh) * (1.0f / 512.0f);
    float rstd = 1.0f / sqrtf(var + LN_EPS);
    float w0 = dynld(lnw, t, f32),       w1 = dynld(lnw, t + 256, f32);
    float b0 = dynld(lnb, t, f32),       b1 = dynld(lnb, t + 256, f32);
    s_n[(size_t)row * D_ + t]       = d0 * rstd * w0 + b0;
    s_n[(size_t)row * D_ + t + 256] = d1 * rstd * w1 + b1;
  }
}

__global__ __launch_bounds__(256) void cast_in(const void* __restrict__ in,
                                               float* __restrict__ out,
                                               const int* __restrict__ flag){
  const bool f32 = (*flag != 0);
  int i = blockIdx.x * 256 + threadIdx.x;
  out[i] = f32 ? ((const float*)in)[i] : b2f(((const ushort_t*)in)[i]);
}

extern "C" void kernel_launch(void* const* d_in, const int* in_sizes, int n_in,
                              void* d_out, int out_size, void* d_ws, size_t ws_size,
                              hipStream_t stream)
{
  const void* in_slots  = d_in[0];
  const void* features  = d_in[1];
  const void* w_k   = d_in[2];
  const void* w_v   = d_in[3];
  const void* w_q   = d_in[4];
  const void* ln_feat_w = d_in[5];
  const void* ln_feat_b = d_in[6];
  const void* ln_slot_w = d_in[7];
  const void* ln_slot_b = d_in[8];
  const void* w_ih  = d_in[9];
  const void* w_hh  = d_in[10];
  const void* b_ih  = d_in[11];
  const void* b_hh  = d_in[12];
  const void* ln_mlp_w = d_in[13];
  const void* ln_mlp_b = d_in[14];
  const void* mlp_w1 = d_in[15];
  const void* mlp_b1 = d_in[16];
  const void* mlp_w2 = d_in[17];
  const void* mlp_b2 = d_in[18];

  float* W     = (float*)d_ws;
  int*   flag  = (int*)d_ws;           // first 64 floats reserved
  float* Wqk   = W + 64;               // 262144
  float* slots = Wqk   + 262144;       // 131072
  float* s_n   = slots + 131072;       // 131072
  float* qkp   = s_n   + 131072;       // 4 x 131072
  float* Ud    = qkp   + 524288;       // 131072
  float* meanb = Ud    + 131072;       // 131072
  float* rstdb = meanb + 131072;       // 131072
  float* gbuf  = rstdb + 131072;       // 131072
  float* gsb   = gbuf  + 131072;       // 256
  float* qbb   = gsb   + 256;          // 256
  float* A1p   = qbb   + 256;          // 512*4096 = 2097152
  float* A2p   = A1p   + 2097152;      // 4096
  float* A3p   = A2p   + 4096;         // 4096
  float* gip   = A3p   + 4096;         // 4 x 393216
  float* ghp   = gip   + 1572864;      // 4 x 393216
  float* lnm   = ghp   + 1572864;      // 131072
  float* snew  = lnm   + 131072;       // 131072
  float* h1p   = snew  + 131072;       // 4 x 524288
  float* h2p   = h1p   + 2097152;      // 8 x 131072
  float* Wqkp  = h2p   + 1048576;      // 1048576 (preamble only)
  float* Wvih  = Wqkp  + 1048576;      // 786432  -> total ~53 MB

  detect_dtype<<<1, 256, 0, stream>>>((const uint32_t*)features, flag);
  cast_in<<<512, 256, 0, stream>>>(in_slots, slots, flag);
  // Wqk = w_q @ w_k^T (split-K 4 + combine)
  gemm64<1, 1, 1, 0><<<dim3(8, 8, 4), 256, 0, stream>>>(
      w_q, w_k, nullptr, Wqkp, 512, 512, 512, 128, 0, flag);
  combine4<<<1024, 256, 0, stream>>>(Wqkp, Wqk, 262144);
  // Wvih = w_v @ w_ih^T  (folds the per-iter upd GEMM out of the loop)
  gemm64<1, 1, 1, 0><<<dim3(8, 24, 1), 256, 0, stream>>>(
      w_v, w_ih, nullptr, Wvih, 512, 1536, 512, 512, 0, flag);
  // per-feature-row LN stats (iteration-invariant)
  ln_stats<<<dim3(32, 32), 256, 0, stream>>>(features, meanb, rstdb, flag);
  // s_n for iteration 0 (later iterations get it from combine_ln)
  ln_rows<<<256, 256, 0, stream>>>(slots, ln_slot_w, ln_slot_b, s_n, flag);

  for (int it = 0; it < 3; ++it){
    // qk partials = s_n @ Wqk
    gemm64<0, 0, 0, 0><<<dim3(4, 8, 4), 256, 0, stream>>>(
        s_n, Wqk, nullptr, qkp, 256, 512, 512, 128, 0, flag);
    qk_prep<<<32, 256, 0, stream>>>(qkp, ln_feat_w, ln_feat_b,
                                    gbuf, gsb, qbb, flag);
    big_pass2<<<dim3(16, 32), 256, 0, stream>>>(
        features, gbuf, gsb, qbb, meanb, rstdb, d_out, A1p, A2p, A3p, flag);
    reduce_updates2<<<256, 256, 0, stream>>>(A1p, A2p, A3p, ln_feat_w,
                                             ln_feat_b, Ud, flag);
    // gi = Ud @ Wvih, gh = s_n @ w_hh^T, fused in one launch (split-K 4 each)
    gemm_gigh<<<dim3(4, 24, 8), 256, 0, stream>>>(
        Ud, Wvih, s_n, w_hh, gip, ghp, flag);
    gru_combine<<<256, 256, 0, stream>>>(gip, ghp, b_ih, b_hh, s_n,
                                         ln_mlp_w, ln_mlp_b, snew, lnm, flag);
    // h1 partials = lnm @ mlp_w1 (bias+relu folded into h2's A-load)
    gemm64<0, 0, 1, 0><<<dim3(4, 32, 4), 256, 0, stream>>>(
        lnm, mlp_w1, nullptr, h1p, 256, 2048, 512, 128, 0, flag);
    // h2 partials = relu(sum(h1p)+b1) @ mlp_w2, split-K 8
    gemm64<0, 0, 1, 1><<<dim3(4, 8, 8), 256, 0, stream>>>(
        h1p, mlp_w2, mlp_b1, h2p, 256, 512, 2048, 256, 524288, flag);
    if (it < 2)
      combine_ln<0><<<256, 256, 0, stream>>>(snew, h2p, mlp_b2, ln_slot_w,
                                             ln_slot_b, s_n, d_out, flag);
    else
      combine_ln<1><<<256, 256, 0, stream>>>(snew, h2p, mlp_b2, ln_slot_w,
                                             ln_slot_b, s_n, d_out, flag);
  }
}